// Round 4
// baseline (320.940 us; speedup 1.0000x reference)
//
#include <hip/hip_runtime.h>

// Problem constants (TokenEmbedding_55997783605696)
#define BATCH    32
#define SEQLEN   4096
#define CIN      7
#define NKERN    74
#define NCOL     512     // 7*73 + 1
#define TT       64      // timesteps per block tile
#define TG       16      // t-group (register blocking)
#define NTAP     24      // collapsed 1D filter length, delta in [-22, +1]
#define HALO     22
#define WROW     25      // W row stride in floats (2-way LDS alias max = free)
#define XROW     88      // xs row stride in floats = TT + 24 (16B-aligned rows)

// out[b,t, c*73+k] = sum_m W[k][m] * x[b, t+m-22, c]
// W[k][m] = kernels[k][7 - m/3][m%3]   (m = 3*(7-i) + j)
// Boundary: x==0 outside [0,L); additionally at t==L-1 all m%3==2 taps with
// m<23 drop (reference's time-axis pad zeroes win[:, L] for every i, even
// where x[t+m-22] itself is in-range). m==23's x is already 0 there.
//
// v5: MEASUREMENT ROUND. Kernel body is v3 verbatim (best: 268.6 us).
// The harness's top-5 counter rows are all ~166-us poison fills; the
// kernel's own dispatch time is invisible, leaving two decompositions of
// dur=270 (kernel ~104 us vs ~62 us) that demand opposite next moves.
// We launch the IDENTICAL kernel twice (second launch rewrites identical
// values -> still correct); Delta-dur vs 268.6 IS the kernel's standalone
// duration. Pre-committed: ~332->near write-floor (ROOFLINE next),
// ~375->2x headroom (restructure next).
__global__ __launch_bounds__(256) void dilated_convbank_kernel(
    const float* __restrict__ x,     // (B, L, C)   fp32
    const float* __restrict__ kern,  // (74, 8, 3)  fp32
    float* __restrict__ out)         // (B, L, 512) fp32
{
    __shared__ __align__(16) float Ws[NKERN * WROW]; // 7.4 KB
    __shared__ __align__(16) float xs[CIN * XROW];   // 2.5 KB

    const int tid = threadIdx.x;
    const int t0  = blockIdx.x * TT;     // 64 tiles
    const int b   = blockIdx.y;          // 32 batches

    // Phase 0: permuted filter load
    for (int idx = tid; idx < NKERN * NTAP; idx += 256) {
        const int k = idx / NTAP, m = idx - k * NTAP;
        const int i = 7 - m / 3, j = m % 3;
        Ws[k * WROW + m] = kern[(k * 8 + i) * 3 + j];
    }
    // Phase 1: x tile, transposed to [c][t_local], zero-padded halo
    for (int idx = tid; idx < CIN * XROW; idx += 256) {
        const int c = idx / XROW, tl = idx - c * XROW;
        const int t = t0 - HALO + tl;
        float v = 0.f;
        if (t >= 0 && t < SEQLEN)
            v = x[(b * SEQLEN + t) * CIN + c];
        xs[c * XROW + tl] = v;
    }
    __syncthreads();

    const bool lastTile = (t0 + TT == SEQLEN);

    #pragma unroll 1
    for (int cc = 0; cc < 2; ++cc) {
        const int q = tid + cc * 256;    // output column 0..511
        int c, k;
        if (q == NCOL - 1) { c = 0; k = NKERN - 1; }
        else               { c = q / 73; k = q - c * 73; }

        float W[NTAP];
        #pragma unroll
        for (int m = 0; m < NTAP; ++m) W[m] = Ws[k * WROW + m];
        const float* xrow = &xs[c * XROW];

        // out base for this column: lanes have consecutive q -> coalesced
        float* ob = out + ((size_t)b * SEQLEN + t0) * NCOL + q;

        #pragma unroll 1
        for (int g = 0; g < TT / TG; ++g) {
            // window xs[c][g*TG .. g*TG+39] via aligned float4 LDS reads
            float xw[TG + NTAP];
            #pragma unroll
            for (int v = 0; v < (TG + NTAP) / 4; ++v) {
                const float4 f = ((const float4*)(xrow + g * TG))[v];
                xw[v * 4 + 0] = f.x; xw[v * 4 + 1] = f.y;
                xw[v * 4 + 2] = f.z; xw[v * 4 + 3] = f.w;
            }
            float acc[TG];
            #pragma unroll
            for (int tt = 0; tt < TG; ++tt) acc[tt] = 0.f;
            #pragma unroll
            for (int m = 0; m < NTAP; ++m) {
                const float w = W[m];
                #pragma unroll
                for (int tt = 0; tt < TG; ++tt)
                    acc[tt] += w * xw[tt + m];
            }
            // t == L-1: drop the j==2 taps whose x is in-range
            if (lastTile && g == TT / TG - 1) {
                #pragma unroll
                for (int m = 2; m < 23; m += 3)
                    acc[TG - 1] -= W[m] * xw[TG - 1 + m];
            }
            #pragma unroll
            for (int tt = 0; tt < TG; ++tt)
                ob[(size_t)(g * TG + tt) * NCOL] = acc[tt];
        }
    }
}

extern "C" void kernel_launch(void* const* d_in, const int* in_sizes, int n_in,
                              void* d_out, int out_size, void* d_ws, size_t ws_size,
                              hipStream_t stream) {
    const float* x    = (const float*)d_in[0]; // (32,4096,7)  fp32
    const float* kern = (const float*)d_in[1]; // (74,8,3)     fp32
    float* out = (float*)d_out;                // (32,4096,512) fp32

    dim3 grid(SEQLEN / TT, BATCH);
    // MEASUREMENT: two identical launches. Second rewrites identical values
    // (idempotent, deterministic) -> correctness preserved. Delta vs the
    // single-launch 268.6 us baseline = kernel standalone duration.
    dilated_convbank_kernel<<<grid, 256, 0, stream>>>(x, kern, out);
    dilated_convbank_kernel<<<grid, 256, 0, stream>>>(x, kern, out);
}

// Round 5
// 267.779 us; speedup vs baseline: 1.1985x; 1.1985x over previous
//
#include <hip/hip_runtime.h>

// Problem constants (TokenEmbedding_55997783605696)
#define BATCH    32
#define SEQLEN   4096
#define CIN      7
#define NKERN    74
#define NCOL     512     // 7*73 + 1
#define TT       64      // timesteps per block tile
#define TG       16      // t-group (register blocking)
#define NTAP     24      // collapsed 1D filter length, delta in [-22, +1]
#define HALO     22
#define WROW     25      // W row stride in floats (2-way LDS alias max = free)
#define XROW     88      // xs row stride in floats = TT + 24 (16B-aligned rows)

// out[b,t, c*73+k] = sum_m W[k][m] * x[b, t+m-22, c]
// W[k][m] = kernels[k][7 - m/3][m%3]   (m = 3*(7-i) + j)
// Boundary: x==0 outside [0,L); additionally at t==L-1 all m%3==2 taps with
// m<23 drop (reference's time-axis pad zeroes win[:, L] for every i, even
// where x[t+m-22] itself is in-range). m==23's x is already 0 there.
//
// v6 = v3 restored (single launch). R4's double-launch probe measured the
// kernel standalone at 52.3 us vs a ~42 us HBM-write floor (268 MB @ the
// 6.4-6.6 TB/s the harness's own fills achieve); the remaining ~216 us of
// dur_us is fixed harness poison-fill time. Store-pattern (v2), tile-size
// (v3), occupancy/nontemporal (v4) all measured neutral -> write-BW-bound.
__global__ __launch_bounds__(256) void dilated_convbank_kernel(
    const float* __restrict__ x,     // (B, L, C)   fp32
    const float* __restrict__ kern,  // (74, 8, 3)  fp32
    float* __restrict__ out)         // (B, L, 512) fp32
{
    __shared__ __align__(16) float Ws[NKERN * WROW]; // 7.4 KB
    __shared__ __align__(16) float xs[CIN * XROW];   // 2.5 KB

    const int tid = threadIdx.x;
    const int t0  = blockIdx.x * TT;     // 64 tiles
    const int b   = blockIdx.y;          // 32 batches

    // Phase 0: permuted filter load
    for (int idx = tid; idx < NKERN * NTAP; idx += 256) {
        const int k = idx / NTAP, m = idx - k * NTAP;
        const int i = 7 - m / 3, j = m % 3;
        Ws[k * WROW + m] = kern[(k * 8 + i) * 3 + j];
    }
    // Phase 1: x tile, transposed to [c][t_local], zero-padded halo
    for (int idx = tid; idx < CIN * XROW; idx += 256) {
        const int c = idx / XROW, tl = idx - c * XROW;
        const int t = t0 - HALO + tl;
        float v = 0.f;
        if (t >= 0 && t < SEQLEN)
            v = x[(b * SEQLEN + t) * CIN + c];
        xs[c * XROW + tl] = v;
    }
    __syncthreads();

    const bool lastTile = (t0 + TT == SEQLEN);

    #pragma unroll 1
    for (int cc = 0; cc < 2; ++cc) {
        const int q = tid + cc * 256;    // output column 0..511
        int c, k;
        if (q == NCOL - 1) { c = 0; k = NKERN - 1; }
        else               { c = q / 73; k = q - c * 73; }

        float W[NTAP];
        #pragma unroll
        for (int m = 0; m < NTAP; ++m) W[m] = Ws[k * WROW + m];
        const float* xrow = &xs[c * XROW];

        // out base for this column: lanes have consecutive q -> coalesced
        float* ob = out + ((size_t)b * SEQLEN + t0) * NCOL + q;

        #pragma unroll 1
        for (int g = 0; g < TT / TG; ++g) {
            // window xs[c][g*TG .. g*TG+39] via aligned float4 LDS reads
            // (g*TG floats = 64 B -> 16B-aligned). ~73 lanes share a channel
            // -> broadcast, conflict-free.
            float xw[TG + NTAP];
            #pragma unroll
            for (int v = 0; v < (TG + NTAP) / 4; ++v) {
                const float4 f = ((const float4*)(xrow + g * TG))[v];
                xw[v * 4 + 0] = f.x; xw[v * 4 + 1] = f.y;
                xw[v * 4 + 2] = f.z; xw[v * 4 + 3] = f.w;
            }
            float acc[TG];
            #pragma unroll
            for (int tt = 0; tt < TG; ++tt) acc[tt] = 0.f;
            #pragma unroll
            for (int m = 0; m < NTAP; ++m) {
                const float w = W[m];
                #pragma unroll
                for (int tt = 0; tt < TG; ++tt)
                    acc[tt] += w * xw[tt + m];
            }
            // t == L-1: drop the j==2 taps whose x is in-range
            if (lastTile && g == TT / TG - 1) {
                #pragma unroll
                for (int m = 2; m < 23; m += 3)
                    acc[TG - 1] -= W[m] * xw[TG - 1 + m];
            }
            #pragma unroll
            for (int tt = 0; tt < TG; ++tt)
                ob[(size_t)(g * TG + tt) * NCOL] = acc[tt];
        }
    }
}

extern "C" void kernel_launch(void* const* d_in, const int* in_sizes, int n_in,
                              void* d_out, int out_size, void* d_ws, size_t ws_size,
                              hipStream_t stream) {
    const float* x    = (const float*)d_in[0]; // (32,4096,7)  fp32
    const float* kern = (const float*)d_in[1]; // (74,8,3)     fp32
    float* out = (float*)d_out;                // (32,4096,512) fp32

    dim3 grid(SEQLEN / TT, BATCH);
    dilated_convbank_kernel<<<grid, 256, 0, stream>>>(x, kern, out);
}